// Round 2
// baseline (1192.085 us; speedup 1.0000x reference)
//
#include <hip/hip_runtime.h>
#include <hip/hip_bf16.h>
#include <math.h>

// B=128, S=2048, H=512, A=512. M = B*S = 262144 tokens.
// out = (output [128,512], alphas [128,2048]) fp32 concat: 65536 + 262144.
//
// Pipeline plan (persistent blocks, continuous HBM streaming):
//   k_wswz      : W fp32 -> bf16, pre-swizzled into MFMA B-frag order
//   k_gemm_fused: 512 persistent blocks x 8 chunks of 64 rows, 512 threads,
//                 double-buffered bf16 X tile in LDS. Loads for chunk c+1 are
//                 issued during epilogue(c-1), drained after GEMM(c); loads for
//                 c+2 issued before epilogue(c) -> HBM queue never empties.
//                 LDS 137.5 KB forces 1 block/CU (2 waves/SIMD), so the wave
//                 may use the full 256-VGPR budget: amdgpu_waves_per_eu(2,2)
//                 pins the allocator there (round-1's 128-VGPR cap spilled
//                 ~70 regs -> 0.9 GB of scratch HBM traffic, 6x slowdown).
//   k_finish    : per batch: merge 32 chunk partials -> output[b,:], then
//                 normalize alphas in place (combine+alphas fused).

#define M_TOK 262144
#define HDIM 512
#define ADIM 512
#define SDIM 2048
#define BDIM 128

#define WSWZ_FLOATS 131072          // 512 KiB bf16 W = 131072 floats of ws
#define PART_STRIDE 514             // o[512], m, l
#define NCHUNK 4096                 // M_TOK / 64
#define NCPB 8                      // chunks per persistent gemm block
#define GEMM_BLOCKS (NCHUNK / NCPB) // 512

typedef __attribute__((ext_vector_type(8))) short short8;   // 8 bf16 (4 VGPRs)
typedef __attribute__((ext_vector_type(4))) float f32x4;    // 4 fp32 acc

static __device__ __forceinline__ unsigned short f2bf(float f) {
    unsigned u = __builtin_bit_cast(unsigned, f);
    unsigned rnd = 0x7FFFu + ((u >> 16) & 1u);
    return (unsigned short)((u + rnd) >> 16);
}

// ---------------------------------------------------------------------------
// k0: W [512][512] fp32 -> bf16 in 16x16x32 B-fragment order.
// Fragment (kb,nb): lane holds W[kb*32 + (lane>>4)*8 + j][nb*16 + (lane&15)].
// ---------------------------------------------------------------------------
__global__ void k_wswz(const float* __restrict__ W, unsigned short* __restrict__ Wswz) {
    int t = blockIdx.x * 256 + threadIdx.x;   // 32768 threads
    int lane = t & 63;
    int frag = t >> 6;                        // frag = kb*32 + nb
    int kb = frag >> 5;
    int nb = frag & 31;
    int n  = nb * 16 + (lane & 15);
    int k0 = kb * 32 + (lane >> 4) * 8;
    short8 s;
#pragma unroll
    for (int j = 0; j < 8; ++j)
        s[j] = (short)f2bf(W[(k0 + j) * ADIM + n]);
    reinterpret_cast<short8*>(Wswz)[t] = s;
}

// ---------------------------------------------------------------------------
// k1: persistent fused GEMM. 512 threads = 8 waves, each wave owns 64 N-cols
// (4 B-frags). LDS: 2 x [64][520] bf16 X tiles (double buffer) = 133 KiB.
// ---------------------------------------------------------------------------
__global__ __launch_bounds__(512)
__attribute__((amdgpu_waves_per_eu(2, 2)))
void k_gemm_fused(const float* __restrict__ X, const unsigned short* __restrict__ Wswz,
                  const float* __restrict__ bvec, const float* __restrict__ u,
                  float* __restrict__ vu, float* __restrict__ part) {
    __shared__ __align__(16) unsigned short Xs[2][64][520];
    __shared__ float vured[8][64];
    __shared__ float e_lds[64];
    __shared__ float opart[512];

    const int tid  = threadIdx.x;
    const int lane = tid & 63;
    const int wave = tid >> 6;
    const int lm   = lane & 15;
    const int quad = lane >> 4;
    const int chunk0 = blockIdx.x * NCPB;

    // chunk = 64 rows x 512 cols fp32 = 8192 float4; thread t loads float4s
    // t, t+512, ... (16 per thread), i.e. fully coalesced.
    const float4* Xp = reinterpret_cast<const float4*>(X) + (size_t)chunk0 * 8192;

    float4 st[16];

    // ---- prologue: stage chunk 0 directly into buffer 0 ----
#pragma unroll
    for (int t = 0; t < 16; ++t) st[t] = Xp[t * 512 + tid];
#pragma unroll
    for (int t = 0; t < 16; ++t) {
        int idx  = t * 512 + tid;
        int row  = idx >> 7;
        int col4 = idx & 127;
        uint2 d;
        d.x = (unsigned)f2bf(st[t].x) | ((unsigned)f2bf(st[t].y) << 16);
        d.y = (unsigned)f2bf(st[t].z) | ((unsigned)f2bf(st[t].w) << 16);
        *reinterpret_cast<uint2*>(&Xs[0][row][col4 * 4]) = d;
    }
    // issue loads for chunk 1 (in flight across the barrier + GEMM(0))
#pragma unroll
    for (int t = 0; t < 16; ++t) st[t] = Xp[8192 + t * 512 + tid];
    __syncthreads();

    // B-frag stream base: frag (kb, nb=wave*4+j) lives at short8 index
    // (kb*32 + nb)*64 + lane.
    const short8* wbl = reinterpret_cast<const short8*>(Wswz) + wave * 256 + lane;

    for (int c = 0; c < NCPB; ++c) {
        const int cur = c & 1;

        // ---- GEMM: 4(M) x 4(N) C-frags per wave, B from L2, 1-kb prefetch --
        f32x4 acc[4][4];
#pragma unroll
        for (int i = 0; i < 4; ++i)
#pragma unroll
            for (int j = 0; j < 4; ++j)
                acc[i][j] = (f32x4){0.f, 0.f, 0.f, 0.f};

        short8 bcur[4], bnxt[4];
#pragma unroll
        for (int j = 0; j < 4; ++j) bcur[j] = wbl[j * 64];

        for (int kb = 0; kb < 16; ++kb) {
            if (kb < 15) {
#pragma unroll
                for (int j = 0; j < 4; ++j) bnxt[j] = wbl[(kb + 1) * 2048 + j * 64];
            }
            short8 a[4];
#pragma unroll
            for (int i = 0; i < 4; ++i)
                a[i] = *reinterpret_cast<const short8*>(&Xs[cur][i * 16 + lm][kb * 32 + quad * 8]);
#pragma unroll
            for (int i = 0; i < 4; ++i)
#pragma unroll
                for (int j = 0; j < 4; ++j)
                    acc[i][j] = __builtin_amdgcn_mfma_f32_16x16x32_bf16(a[i], bcur[j], acc[i][j], 0, 0, 0);
#pragma unroll
            for (int j = 0; j < 4; ++j) bcur[j] = bnxt[j];
        }

        // ---- drain chunk c+1 loads -> other LDS buffer (write-late) ----
        if (c + 1 < NCPB) {
#pragma unroll
            for (int t = 0; t < 16; ++t) {
                int idx  = t * 512 + tid;
                int row  = idx >> 7;
                int col4 = idx & 127;
                uint2 d;
                d.x = (unsigned)f2bf(st[t].x) | ((unsigned)f2bf(st[t].y) << 16);
                d.y = (unsigned)f2bf(st[t].z) | ((unsigned)f2bf(st[t].w) << 16);
                *reinterpret_cast<uint2*>(&Xs[cur ^ 1][row][col4 * 4]) = d;
            }
        }
        // ---- issue chunk c+2 loads (keep HBM busy through the epilogues) --
        if (c + 2 < NCPB) {
            const float4* Xp2 = Xp + (size_t)(c + 2) * 8192;
#pragma unroll
            for (int t = 0; t < 16; ++t) st[t] = Xp2[t * 512 + tid];
        }

        // ---- epilogue A: tanh(acc + b) dot u, reduce to per-row vu ----
        float vus[16];
#pragma unroll
        for (int q = 0; q < 16; ++q) vus[q] = 0.f;
#pragma unroll
        for (int j = 0; j < 4; ++j) {
            int col  = wave * 64 + j * 16 + lm;
            float uu = u[col];
            float bb = bvec[col];
#pragma unroll
            for (int i = 0; i < 4; ++i)
#pragma unroll
                for (int r = 0; r < 4; ++r) {
                    float x = acc[i][j][r] + bb;
                    float e = __expf(2.0f * x);        // inf-safe tanh
                    float t = 1.0f - 2.0f / (e + 1.0f);
                    vus[i * 4 + r] += t * uu;
                }
        }
#pragma unroll
        for (int m = 1; m <= 8; m <<= 1) {
#pragma unroll
            for (int q = 0; q < 16; ++q)
                vus[q] += __shfl_xor(vus[q], m, 64);
        }
        if (lm == 0) {
#pragma unroll
            for (int i = 0; i < 4; ++i)
#pragma unroll
                for (int r = 0; r < 4; ++r)
                    vured[wave][i * 16 + quad * 4 + r] = vus[i * 4 + r];
        }
        __syncthreads();

        // ---- epilogue B: chunk softmax (m, l, e_s) by wave 0 ----
        const int chunk = chunk0 + c;
        float* pblk = part + (size_t)chunk * PART_STRIDE;
        if (tid < 64) {
            float v = (vured[0][tid] + vured[1][tid] + vured[2][tid] + vured[3][tid] +
                       vured[4][tid] + vured[5][tid] + vured[6][tid] + vured[7][tid])
                      * 0.044194173824159216f;          // 1/sqrt(512)
            vu[chunk * 64 + tid] = v;
            float m = v;
#pragma unroll
            for (int j = 1; j <= 32; j <<= 1) m = fmaxf(m, __shfl_xor(m, j, 64));
            float e = __expf(v - m);
            e_lds[tid] = e;
            float l = e;
#pragma unroll
            for (int j = 1; j <= 32; j <<= 1) l += __shfl_xor(l, j, 64);
            if (tid == 0) { pblk[512] = m; pblk[513] = l; }
        }
        __syncthreads();

        // ---- epilogue C: o[h] = sum_s e_s * x[s][h], s-range split in half --
        {
            const int half = tid >> 8;                 // 0: s=0..31, 1: s=32..63
            const int c2   = (tid & 255) * 2;          // two adjacent columns
            const int s0   = half * 32;
            float o0 = 0.f, o1 = 0.f;
#pragma unroll 8
            for (int s = 0; s < 32; ++s) {
                unsigned uu = *reinterpret_cast<const unsigned*>(&Xs[cur][s0 + s][c2]);
                float e  = e_lds[s0 + s];              // LDS broadcast
                float xl = __builtin_bit_cast(float, uu << 16);
                float xh = __builtin_bit_cast(float, uu & 0xFFFF0000u);
                o0 = fmaf(e, xl, o0);
                o1 = fmaf(e, xh, o1);
            }
            if (half) { opart[c2] = o0; opart[c2 + 1] = o1; }
            __syncthreads();
            if (!half) {
                o0 += opart[c2];
                o1 += opart[c2 + 1];
                *reinterpret_cast<float2*>(&pblk[c2]) = make_float2(o0, o1);
            }
        }
        __syncthreads();   // protects Xs[cur] (next iter drains into it),
                           // e_lds, opart, vured across iterations
    }
}

// ---------------------------------------------------------------------------
// k2: per batch: merge 32 chunk partials -> output[b,:]; normalize alphas
// in place (fused combine + alphas).
// ---------------------------------------------------------------------------
__global__ __launch_bounds__(256)
void k_finish(const float* __restrict__ part, float* __restrict__ out,
              float* __restrict__ alphas) {
    const int b = blockIdx.x, tid = threadIdx.x;
    __shared__ float wch[32];
    __shared__ float sM, sI;
    const float* pb = part + (size_t)b * 32 * PART_STRIDE;
    if (tid < 32) {
        float m = pb[tid * PART_STRIDE + 512];
        float l = pb[tid * PART_STRIDE + 513];
        float M = m;
#pragma unroll
        for (int j = 1; j <= 16; j <<= 1) M = fmaxf(M, __shfl_xor(M, j, 32));
        float w  = __expf(m - M);
        float lw = l * w;
#pragma unroll
        for (int j = 1; j <= 16; j <<= 1) lw += __shfl_xor(lw, j, 32);
        wch[tid] = w;
        if (tid == 0) { sM = M; sI = 1.0f / (lw + 1e-10f); }
    }
    __syncthreads();
    const float M = sM, inv = sI;

    // output[b, h] = inv * sum_c w_c * o_c[h]
    float o0 = 0.f, o1 = 0.f;
    const int h = tid * 2;
#pragma unroll 8
    for (int c = 0; c < 32; ++c) {
        float w = wch[c];
        float2 v = *reinterpret_cast<const float2*>(&pb[c * PART_STRIDE + h]);
        o0 = fmaf(w, v.x, o0);
        o1 = fmaf(w, v.y, o1);
    }
    out[b * HDIM + h]     = o0 * inv;
    out[b * HDIM + h + 1] = o1 * inv;

    // alphas[b, s] = exp(vu - M) * inv, in place (vectorized RMW)
    float4* ab = reinterpret_cast<float4*>(alphas + (size_t)b * SDIM);
#pragma unroll
    for (int k = 0; k < 2; ++k) {
        float4 v = ab[tid + k * 256];
        v.x = __expf(v.x - M) * inv;
        v.y = __expf(v.y - M) * inv;
        v.z = __expf(v.z - M) * inv;
        v.w = __expf(v.w - M) * inv;
        ab[tid + k * 256] = v;
    }
}

extern "C" void kernel_launch(void* const* d_in, const int* in_sizes, int n_in,
                              void* d_out, int out_size, void* d_ws, size_t ws_size,
                              hipStream_t stream) {
    const float* X  = (const float*)d_in[0];   // [128,2048,512]
    const float* W  = (const float*)d_in[1];   // [512,512]
    const float* bb = (const float*)d_in[2];   // [512]
    const float* u  = (const float*)d_in[3];   // [512]
    float* out = (float*)d_out;                // [65536 output | 262144 alphas]

    unsigned short* Wswz = (unsigned short*)d_ws;
    float* part = (float*)d_ws + WSWZ_FLOATS;  // 4096*514 floats

    k_wswz<<<128, 256, 0, stream>>>(W, Wswz);
    k_gemm_fused<<<GEMM_BLOCKS, 512, 0, stream>>>(X, Wswz, bb, u, out + 65536, part);
    k_finish<<<BDIM, 256, 0, stream>>>(part, out, out + 65536);
}

// Round 3
// 1021.417 us; speedup vs baseline: 1.1671x; 1.1671x over previous
//
#include <hip/hip_runtime.h>
#include <hip/hip_bf16.h>
#include <math.h>

// B=128, S=2048, H=512, A=512. M = B*S = 262144 tokens.
// out = (output [128,512], alphas [128,2048]) fp32 concat: 65536 + 262144.
//
// Pipeline plan (persistent blocks, continuous HBM streaming):
//   k_wswz      : W fp32 -> bf16, pre-swizzled into MFMA B-frag order
//   k_gemm_fused: 256 persistent blocks x 16 chunks of 64 rows, 1024 threads
//                 (16 waves, 1 block/CU, 4 waves/SIMD -> 128-VGPR budget).
//                 Double-buffered bf16 X tile in LDS. Loads for chunk c+1
//                 are in flight across GEMM(c); drained after GEMM(c); loads
//                 for c+2 issued before the epilogues -> HBM queue never
//                 empties. Designed to fit 128 VGPRs (the allocator's pick
//                 at this block size): st[8]=32 + acc[4][2]=32 + b-frags 16
//                 + temps ~= 115. Rounds 1-2 demanded ~210 regs at 512 thr
//                 and spilled ~30/iter -> 0.85 GB scratch HBM traffic.
//   k_finish    : per batch: merge 32 chunk partials -> output[b,:], then
//                 normalize alphas in place (combine+alphas fused).

#define M_TOK 262144
#define HDIM 512
#define ADIM 512
#define SDIM 2048
#define BDIM 128

#define WSWZ_FLOATS 131072           // 512 KiB bf16 W = 131072 floats of ws
#define PART_STRIDE 514              // o[512], m, l
#define NCHUNK 4096                  // M_TOK / 64
#define NCPB 16                      // chunks per persistent gemm block
#define GEMM_BLOCKS (NCHUNK / NCPB)  // 256 = one per CU

typedef __attribute__((ext_vector_type(8))) short short8;   // 8 bf16 (4 VGPRs)
typedef __attribute__((ext_vector_type(4))) float f32x4;    // 4 fp32 acc

static __device__ __forceinline__ unsigned f2bf(float f) {
    unsigned u = __builtin_bit_cast(unsigned, f);
    unsigned rnd = 0x7FFFu + ((u >> 16) & 1u);
    return (u + rnd) >> 16;
}

// ---------------------------------------------------------------------------
// k0: W [512][512] fp32 -> bf16 in 16x16x32 B-fragment order.
// Fragment (kb,nb): lane holds W[kb*32 + (lane>>4)*8 + j][nb*16 + (lane&15)].
// ---------------------------------------------------------------------------
__global__ void k_wswz(const float* __restrict__ W, unsigned short* __restrict__ Wswz) {
    int t = blockIdx.x * 256 + threadIdx.x;   // 32768 threads
    int lane = t & 63;
    int frag = t >> 6;                        // frag = kb*32 + nb
    int kb = frag >> 5;
    int nb = frag & 31;
    int n  = nb * 16 + (lane & 15);
    int k0 = kb * 32 + (lane >> 4) * 8;
    short8 s;
#pragma unroll
    for (int j = 0; j < 8; ++j)
        s[j] = (short)f2bf(W[(k0 + j) * ADIM + n]);
    reinterpret_cast<short8*>(Wswz)[t] = s;
}

// ---------------------------------------------------------------------------
// k1: persistent fused GEMM. 1024 threads = 16 waves; wave w owns N-cols
// [w*32, w*32+32) (2 B-frags) across all 64 rows (4 M-frags).
// LDS: 2 x [64][520] bf16 X tiles (133 KiB) + reductions = 143.6 KiB.
// ---------------------------------------------------------------------------
__global__ __launch_bounds__(1024, 4)
void k_gemm_fused(const float* __restrict__ X, const unsigned short* __restrict__ Wswz,
                  const float* __restrict__ bvec, const float* __restrict__ u,
                  float* __restrict__ vu, float* __restrict__ part) {
    __shared__ __align__(16) unsigned short Xs[2][64][520];
    __shared__ float vured[16][64];
    __shared__ float e_lds[64];
    __shared__ float opart[3][512];

    const int tid  = threadIdx.x;             // 0..1023
    const int lane = tid & 63;
    const int wave = tid >> 6;                // 0..15
    const int lm   = lane & 15;
    const int quad = lane >> 4;
    const int chunk0 = blockIdx.x * NCPB;

    // chunk = 64 rows x 512 cols fp32 = 8192 float4; thread t loads float4s
    // tid, tid+1024, ... (8 per thread), fully coalesced.
    const float4* Xp = reinterpret_cast<const float4*>(X) + (size_t)chunk0 * 8192;

    // hoisted per-thread u/b for this wave's two N-frag columns
    const int col0 = wave * 32 + lm;
    const float uu0 = u[col0],    uu1 = u[col0 + 16];
    const float bb0 = bvec[col0], bb1 = bvec[col0 + 16];

    float4 st[8];

    // ---- prologue: stage chunk 0 directly into buffer 0 ----
#pragma unroll
    for (int t = 0; t < 8; ++t) st[t] = Xp[t * 1024 + tid];
#pragma unroll
    for (int t = 0; t < 8; ++t) {
        int idx  = t * 1024 + tid;
        int row  = idx >> 7;
        int col4 = idx & 127;
        uint2 d;
        d.x = f2bf(st[t].x) | (f2bf(st[t].y) << 16);
        d.y = f2bf(st[t].z) | (f2bf(st[t].w) << 16);
        *reinterpret_cast<uint2*>(&Xs[0][row][col4 * 4]) = d;
    }
    // issue loads for chunk 1 (in flight across the barrier + GEMM(0))
#pragma unroll
    for (int t = 0; t < 8; ++t) st[t] = Xp[8192 + t * 1024 + tid];
    __syncthreads();

    // B-frag stream: frag (kb, nb=2*wave+j) lives at short8 index
    // kb*2048 + wave*128 + j*64 + lane.
    const short8* wbl = reinterpret_cast<const short8*>(Wswz) + wave * 128 + lane;

    for (int c = 0; c < NCPB; ++c) {
        const int cur = c & 1;

        // ---- GEMM: 4(M) x 2(N) C-frags per wave, B from L2, 1-kb prefetch --
        f32x4 acc[4][2];
#pragma unroll
        for (int i = 0; i < 4; ++i) {
            acc[i][0] = (f32x4){0.f, 0.f, 0.f, 0.f};
            acc[i][1] = (f32x4){0.f, 0.f, 0.f, 0.f};
        }

        short8 bcur[2], bnxt[2];
        bcur[0] = wbl[0];
        bcur[1] = wbl[64];

        for (int kb = 0; kb < 16; ++kb) {
            if (kb < 15) {
                bnxt[0] = wbl[(kb + 1) * 2048];
                bnxt[1] = wbl[(kb + 1) * 2048 + 64];
            }
#pragma unroll
            for (int i = 0; i < 4; ++i) {
                short8 a = *reinterpret_cast<const short8*>(&Xs[cur][i * 16 + lm][kb * 32 + quad * 8]);
                acc[i][0] = __builtin_amdgcn_mfma_f32_16x16x32_bf16(a, bcur[0], acc[i][0], 0, 0, 0);
                acc[i][1] = __builtin_amdgcn_mfma_f32_16x16x32_bf16(a, bcur[1], acc[i][1], 0, 0, 0);
            }
            bcur[0] = bnxt[0];
            bcur[1] = bnxt[1];
        }

        // ---- drain chunk c+1 loads -> other LDS buffer (write-late) ----
        if (c + 1 < NCPB) {
#pragma unroll
            for (int t = 0; t < 8; ++t) {
                int idx  = t * 1024 + tid;
                int row  = idx >> 7;
                int col4 = idx & 127;
                uint2 d;
                d.x = f2bf(st[t].x) | (f2bf(st[t].y) << 16);
                d.y = f2bf(st[t].z) | (f2bf(st[t].w) << 16);
                *reinterpret_cast<uint2*>(&Xs[cur ^ 1][row][col4 * 4]) = d;
            }
        }
        // ---- issue chunk c+2 loads (keep HBM busy through the epilogues) --
        if (c + 2 < NCPB) {
            const float4* Xp2 = Xp + (size_t)(c + 2) * 8192;
#pragma unroll
            for (int t = 0; t < 8; ++t) st[t] = Xp2[t * 1024 + tid];
        }

        // ---- epilogue A: tanh(acc + b) dot u, reduce to per-row vu ----
        float vus[16];
#pragma unroll
        for (int i = 0; i < 4; ++i)
#pragma unroll
            for (int r = 0; r < 4; ++r) {
                float x0 = acc[i][0][r] + bb0;
                float e0 = __expf(2.0f * x0);          // inf-safe tanh
                float t0 = 1.0f - 2.0f / (e0 + 1.0f);
                float x1 = acc[i][1][r] + bb1;
                float e1 = __expf(2.0f * x1);
                float t1 = 1.0f - 2.0f / (e1 + 1.0f);
                vus[i * 4 + r] = fmaf(t0, uu0, t1 * uu1);
            }
#pragma unroll
        for (int m = 1; m <= 8; m <<= 1) {
#pragma unroll
            for (int q = 0; q < 16; ++q)
                vus[q] += __shfl_xor(vus[q], m, 64);
        }
        if (lm == 0) {
#pragma unroll
            for (int i = 0; i < 4; ++i)
#pragma unroll
                for (int r = 0; r < 4; ++r)
                    vured[wave][i * 16 + quad * 4 + r] = vus[i * 4 + r];
        }
        __syncthreads();

        // ---- epilogue B: chunk softmax (m, l, e_s) by wave 0 ----
        const int chunk = chunk0 + c;
        float* pblk = part + (size_t)chunk * PART_STRIDE;
        if (tid < 64) {
            float v = 0.f;
#pragma unroll
            for (int w = 0; w < 16; ++w) v += vured[w][tid];
            v *= 0.044194173824159216f;                 // 1/sqrt(512)
            vu[chunk * 64 + tid] = v;
            float m = v;
#pragma unroll
            for (int j = 1; j <= 32; j <<= 1) m = fmaxf(m, __shfl_xor(m, j, 64));
            float e = __expf(v - m);
            e_lds[tid] = e;
            float l = e;
#pragma unroll
            for (int j = 1; j <= 32; j <<= 1) l += __shfl_xor(l, j, 64);
            if (tid == 0) { pblk[512] = m; pblk[513] = l; }
        }
        __syncthreads();

        // ---- epilogue C: o[h] = sum_s e_s * x[s][h]; s split in 4 quarters -
        {
            const int q  = tid >> 8;                    // quarter: s range of 16
            const int c2 = (tid & 255) * 2;             // two adjacent columns
            const int s0 = q * 16;
            float o0 = 0.f, o1 = 0.f;
#pragma unroll 8
            for (int s = 0; s < 16; ++s) {
                unsigned uu = *reinterpret_cast<const unsigned*>(&Xs[cur][s0 + s][c2]);
                float e  = e_lds[s0 + s];               // LDS broadcast
                float xl = __builtin_bit_cast(float, uu << 16);
                float xh = __builtin_bit_cast(float, uu & 0xFFFF0000u);
                o0 = fmaf(e, xl, o0);
                o1 = fmaf(e, xh, o1);
            }
            if (q > 0) { opart[q - 1][c2] = o0; opart[q - 1][c2 + 1] = o1; }
            __syncthreads();
            if (q == 0) {
                o0 += opart[0][c2] + opart[1][c2] + opart[2][c2];
                o1 += opart[0][c2 + 1] + opart[1][c2 + 1] + opart[2][c2 + 1];
                *reinterpret_cast<float2*>(&pblk[c2]) = make_float2(o0, o1);
            }
        }
        __syncthreads();   // protects Xs[cur] (next iter drains into it),
                           // e_lds, opart, vured across iterations
    }
}

// ---------------------------------------------------------------------------
// k2: per batch: merge 32 chunk partials -> output[b,:]; normalize alphas
// in place (fused combine + alphas).
// ---------------------------------------------------------------------------
__global__ __launch_bounds__(256)
void k_finish(const float* __restrict__ part, float* __restrict__ out,
              float* __restrict__ alphas) {
    const int b = blockIdx.x, tid = threadIdx.x;
    __shared__ float wch[32];
    __shared__ float sM, sI;
    const float* pb = part + (size_t)b * 32 * PART_STRIDE;
    if (tid < 32) {
        float m = pb[tid * PART_STRIDE + 512];
        float l = pb[tid * PART_STRIDE + 513];
        float M = m;
#pragma unroll
        for (int j = 1; j <= 16; j <<= 1) M = fmaxf(M, __shfl_xor(M, j, 32));
        float w  = __expf(m - M);
        float lw = l * w;
#pragma unroll
        for (int j = 1; j <= 16; j <<= 1) lw += __shfl_xor(lw, j, 32);
        wch[tid] = w;
        if (tid == 0) { sM = M; sI = 1.0f / (lw + 1e-10f); }
    }
    __syncthreads();
    const float M = sM, inv = sI;

    // output[b, h] = inv * sum_c w_c * o_c[h]
    float o0 = 0.f, o1 = 0.f;
    const int h = tid * 2;
#pragma unroll 8
    for (int c = 0; c < 32; ++c) {
        float w = wch[c];
        float2 v = *reinterpret_cast<const float2*>(&pb[c * PART_STRIDE + h]);
        o0 = fmaf(w, v.x, o0);
        o1 = fmaf(w, v.y, o1);
    }
    out[b * HDIM + h]     = o0 * inv;
    out[b * HDIM + h + 1] = o1 * inv;

    // alphas[b, s] = exp(vu - M) * inv, in place (vectorized RMW)
    float4* ab = reinterpret_cast<float4*>(alphas + (size_t)b * SDIM);
#pragma unroll
    for (int k = 0; k < 2; ++k) {
        float4 v = ab[tid + k * 256];
        v.x = __expf(v.x - M) * inv;
        v.y = __expf(v.y - M) * inv;
        v.z = __expf(v.z - M) * inv;
        v.w = __expf(v.w - M) * inv;
        ab[tid + k * 256] = v;
    }
}

extern "C" void kernel_launch(void* const* d_in, const int* in_sizes, int n_in,
                              void* d_out, int out_size, void* d_ws, size_t ws_size,
                              hipStream_t stream) {
    const float* X  = (const float*)d_in[0];   // [128,2048,512]
    const float* W  = (const float*)d_in[1];   // [512,512]
    const float* bb = (const float*)d_in[2];   // [512]
    const float* u  = (const float*)d_in[3];   // [512]
    float* out = (float*)d_out;                // [65536 output | 262144 alphas]

    unsigned short* Wswz = (unsigned short*)d_ws;
    float* part = (float*)d_ws + WSWZ_FLOATS;  // 4096*514 floats

    k_wswz<<<128, 256, 0, stream>>>(W, Wswz);
    k_gemm_fused<<<GEMM_BLOCKS, 1024, 0, stream>>>(X, Wswz, bb, u, out + 65536, part);
    k_finish<<<BDIM, 256, 0, stream>>>(part, out, out + 65536);
}